// Round 1
// baseline (231.831 us; speedup 1.0000x reference)
//
#include <hip/hip_runtime.h>

// Problem constants (reference: B=64, T=512, D=1024, U=128)
#define BB 64
#define TT 512
#define DD 1024
#define UU 128
#define MM (BB * TT)        // 32768 rows
#define BK 64               // K-chunk
#define NCHUNK (DD / BK)    // 16
#define LDA 72              // LDS row stride in bf16 elems (144 B = 128+16 -> 2-way b128 reads, free)
#define LDB 72

typedef short short8 __attribute__((ext_vector_type(8)));   // 8 bf16 in 4 VGPRs (MFMA A/B frag)
typedef float f32x4 __attribute__((ext_vector_type(4)));    // MFMA C/D frag

// fp32 -> bf16, round-to-nearest-even (inputs are finite random normals; no NaN path needed)
__device__ __forceinline__ unsigned short f2bf(float f) {
    union { float f; unsigned u; } v; v.f = f;
    unsigned u = v.u;
    return (unsigned short)((u + 0x7fffu + ((u >> 16) & 1u)) >> 16);
}

// ---------------------------------------------------------------------------
// Kernel 0: convert W[k][n] (fp32, 1024x128) into ws as bf16, transposed and
// chunked: wt[kc*8192 + n*64 + k'] = bf16(W[kc*64+k'][n]).
// This makes GEMM B-staging a pure contiguous 16B copy (no transpose, no cvt).
// 16384 threads, each emits one 16B chunk (8 bf16), fully coalesced writes.
// ---------------------------------------------------------------------------
__global__ __launch_bounds__(256) void wprep_kernel(const float* __restrict__ w,
                                                    unsigned short* __restrict__ wt) {
    int tg = blockIdx.x * 256 + threadIdx.x;   // 0..16383
    int kg = tg & 7;                           // 16B group within a row of 64 k'
    int n  = (tg >> 3) & 127;
    int kc = tg >> 10;
    union { unsigned short s[8]; uint4 v; } o;
#pragma unroll
    for (int j = 0; j < 8; ++j) {
        int k = kc * 64 + kg * 8 + j;
        o.s[j] = f2bf(w[k * 128 + n]);         // strided read (L2-resident, W = 512 KiB)
    }
    *(uint4*)(wt + tg * 8) = o.v;              // coalesced 16B write
}

// ---------------------------------------------------------------------------
// Kernel 1: energy = bf16_mfma(x @ W) + bias + start*left + end*right
// Tile: 64(M) x 128(N) per block, 256 threads = 4 waves, each wave 32x64.
// ---------------------------------------------------------------------------
__global__ __launch_bounds__(256, 2) void crf_energy_kernel(
    const float* __restrict__ x,               // [32768, 1024]
    const int* __restrict__ mask,              // [32768] ([B,T])
    const unsigned short* __restrict__ wt,     // ws: bf16 Wt chunks
    const float* __restrict__ bias,            // [128]
    const float* __restrict__ lb,              // [128]
    const float* __restrict__ rb,              // [128]
    float* __restrict__ out)                   // [32768, 128]
{
    __shared__ unsigned short lA[64 * LDA];    // 9216 * 2B  = 18 KiB
    __shared__ unsigned short lB[128 * LDB];   // 18432 * 2B (incl pad; pads never read by frags)

    const int tid  = threadIdx.x;
    const int wave = tid >> 6;
    const int lane = tid & 63;
    const int q    = lane >> 4;                // quad 0..3
    const int r    = lane & 15;
    const int row0 = blockIdx.x * 64;

    const int mhalf = wave >> 1;               // wave's 32-row half
    const int nhalf = wave & 1;                // wave's 64-col half

    f32x4 acc[2][4];                           // [mt][nt], 16x16 tiles
#pragma unroll
    for (int i = 0; i < 2; ++i)
#pragma unroll
        for (int j = 0; j < 4; ++j) acc[i][j] = (f32x4){0.f, 0.f, 0.f, 0.f};

    for (int kc = 0; kc < NCHUNK; ++kc) {
        // ---- stage A: 64 rows x 64 k of fp32 -> bf16 LDS. 1024 float4 chunks.
#pragma unroll
        for (int p = 0; p < 4; ++p) {
            int c  = p * 256 + tid;            // 0..1023
            int m  = c >> 4;                   // 0..63
            int kg = c & 15;                   // float4 group within row
            const float4 v = *(const float4*)(x + (size_t)(row0 + m) * DD + kc * BK + kg * 4);
            union { unsigned short s[4]; unsigned long long u; } pk;
            pk.s[0] = f2bf(v.x); pk.s[1] = f2bf(v.y);
            pk.s[2] = f2bf(v.z); pk.s[3] = f2bf(v.w);
            *(unsigned long long*)(&lA[m * LDA + kg * 4]) = pk.u;   // 8B LDS write
        }
        // ---- stage B: 128 rows(n) x 64 k' bf16, contiguous 16B copies from ws.
#pragma unroll
        for (int p = 0; p < 4; ++p) {
            int c  = p * 256 + tid;            // 0..1023
            int n  = c >> 3;                   // 0..127
            int kg = c & 7;
            uint4 v = *(const uint4*)(wt + (size_t)kc * 8192 + n * 64 + kg * 8);
            *(uint4*)(&lB[n * LDB + kg * 8]) = v;
        }
        __syncthreads();

        // ---- MFMA: 2 k-steps of 32, 2x4 tiles per wave
#pragma unroll
        for (int ks = 0; ks < 2; ++ks) {
            short8 a[2], b[4];
#pragma unroll
            for (int mt = 0; mt < 2; ++mt)
                a[mt] = *(const short8*)(&lA[(mhalf * 32 + mt * 16 + r) * LDA + ks * 32 + q * 8]);
#pragma unroll
            for (int nt = 0; nt < 4; ++nt)
                b[nt] = *(const short8*)(&lB[(nhalf * 64 + nt * 16 + r) * LDB + ks * 32 + q * 8]);
#pragma unroll
            for (int mt = 0; mt < 2; ++mt)
#pragma unroll
                for (int nt = 0; nt < 4; ++nt)
                    acc[mt][nt] = __builtin_amdgcn_mfma_f32_16x16x32_bf16(
                        a[mt], b[nt], acc[mt][nt], 0, 0, 0);
        }
        __syncthreads();
    }

    // ---- epilogue: bias + boundary masks, coalesced stores.
    // C/D layout (verified m89): col = lane&15 (N), row = quad*4 + reg (M).
#pragma unroll
    for (int mt = 0; mt < 2; ++mt) {
#pragma unroll
        for (int nt = 0; nt < 4; ++nt) {
            const int n = nhalf * 64 + nt * 16 + r;
            const float bi = bias[n];
            const float lbn = lb[n];
            const float rbn = rb[n];
#pragma unroll
            for (int reg = 0; reg < 4; ++reg) {
                const int m = row0 + mhalf * 32 + mt * 16 + q * 4 + reg;
                const int t = m & (TT - 1);
                const int cur  = mask[m];
                const int prev = (t != 0)      ? mask[m - 1] : 0;
                const int nxt  = (t != TT - 1) ? mask[m + 1] : 0;
                float e = acc[mt][nt][reg] + bi;
                if (cur > prev) e += lbn;    // start_mask
                if (nxt > cur)  e += rbn;    // end_mask
                out[(size_t)m * UU + n] = e;
            }
        }
    }
}

extern "C" void kernel_launch(void* const* d_in, const int* in_sizes, int n_in,
                              void* d_out, int out_size, void* d_ws, size_t ws_size,
                              hipStream_t stream) {
    const float* x    = (const float*)d_in[0];
    const int*   mask = (const int*)d_in[1];
    const float* w    = (const float*)d_in[2];
    const float* bias = (const float*)d_in[3];
    const float* lb   = (const float*)d_in[4];
    const float* rb   = (const float*)d_in[5];
    float* out = (float*)d_out;
    unsigned short* wt = (unsigned short*)d_ws;   // 256 KiB of bf16 Wt

    // W fp32 -> bf16, transposed+chunked into ws (re-done every call; ws is re-poisoned)
    wprep_kernel<<<64, 256, 0, stream>>>(w, wt);
    // Main fused GEMM + epilogue: 32768/64 = 512 blocks (2 per CU)
    crf_energy_kernel<<<512, 256, 0, stream>>>(x, mask, wt, bias, lb, rb, out);
}